// Round 2
// baseline (234.946 us; speedup 1.0000x reference)
//
#include <hip/hip_runtime.h>

// ROI bilinear pooling (tf.image.resize half-pixel centers), POOL=7.
// img: (1, 64, 64, 1024) fp32, NHWC. rois: (1, R, 4) int32 = [x, y, w, h].
// out: (1, R, 7, 7, 1024) fp32.
//
// R6 = occupancy restructure. R5 post-mortem: read-path theories are dead
// (image is 16.7 MB, fully L3-resident; sort ~ neutral). Pool kernel runs
// ~107us = 1.9 TB/s effective writes vs the fill's 6.7 TB/s on the same
// path -> not traffic-bound. Suspect: 28 live v4f taps + 64-bit addr
// temps under __launch_bounds__(256,1) pushed VGPR >256 -> 1 block/CU,
// 12.5% occupancy, bursty stores, no cross-block overlap.
// Change: per-px stream (4 live taps), 32-bit element offsets,
// __launch_bounds__(256,4) -> <=128 VGPR -> 4 blocks/CU. Compiler may
// hoist loads a few px deep within the budget (that's the point).
// Sort + XCD chunking kept (concurrent window/XCD ~18 ROIs; sorted
// y-band fits 4 MB L2). Plain stores (R4 A/B).

#define POOLSZ 7
#define IMG_H 64
#define IMG_W 64
#define IMG_C 1024
#define NUM_XCD 8

typedef float v4f __attribute__((ext_vector_type(4)));

// Counting-sort ROI indices by y into order[] (workspace). One block, ~3 us.
__global__ __launch_bounds__(256) void roi_sort_kernel(
    const int* __restrict__ rois, int* __restrict__ order, int R) {
    __shared__ int cnt[64];
    __shared__ int ofs[64];
    const int t = threadIdx.x;
    if (t < 64) cnt[t] = 0;
    __syncthreads();
    for (int r = t; r < R; r += 256) {
        const int y = rois[r * 4 + 1] & 63;
        atomicAdd(&cnt[y], 1);
    }
    __syncthreads();
    if (t == 0) {
        int s = 0;
        for (int i = 0; i < 64; ++i) { ofs[i] = s; s += cnt[i]; }
    }
    __syncthreads();
    for (int r = t; r < R; r += 256) {
        const int y = rois[r * 4 + 1] & 63;
        const int p = atomicAdd(&ofs[y], 1);
        order[p] = r;   // permutation of 0..R-1 by construction
    }
}

// One block per (roi, py) row: 7 output cells. 256 threads, each owns a
// float4 channel slice. Streaming per-px: 4 taps -> blend -> store.
__global__ __launch_bounds__(256, 4) void roi_pool_row_kernel(
    const float* __restrict__ img,
    const int* __restrict__ rois,
    float* __restrict__ out,
    int roisPerXcd,              // R/8 when R%8==0, else 0 (identity mapping)
    const int* __restrict__ order) {  // y-sorted ROI permutation, or null
    int rIdx, py;
    if (roisPerXcd > 0) {
        const int xcd   = blockIdx.x & (NUM_XCD - 1);
        const int local = blockIdx.x >> 3;           // 0 .. R/8*7-1
        rIdx = xcd * roisPerXcd + local / POOLSZ;
        py   = local % POOLSZ;
    } else {
        rIdx = blockIdx.x / POOLSZ;
        py   = blockIdx.x % POOLSZ;
    }
    const int r = order ? order[rIdx] : rIdx;   // spatial (y-band) ordering

    const int4 roi = ((const int4*)rois)[r];
    const int rx = roi.x, ry = roi.y, rw = roi.z, rh = roi.w;

    // y coords: src = (py+0.5)*h/7 - 0.5; lerp from unclipped floor (ref semantics)
    const float scy  = (float)rh * (1.0f / (float)POOLSZ);
    const float srcy = ((float)py + 0.5f) * scy - 0.5f;
    const float fy   = floorf(srcy);
    const float ty   = srcy - fy;
    const int   iy   = (int)fy;
    const int   y0   = ry + min(max(iy,     0), rh - 1);
    const int   y1   = ry + min(max(iy + 1, 0), rh - 1);

    const int c4 = threadIdx.x;                       // 0..255: float4 channel slice
    const v4f* __restrict__ base = (const v4f*)img + c4;
    const int rb0 = y0 * (IMG_W * IMG_C / 4);         // 32-bit v4f-element offsets
    const int rb1 = y1 * (IMG_W * IMG_C / 4);

    v4f* __restrict__ dst =
        (v4f*)out + ((size_t)r * POOLSZ + py) * POOLSZ * (IMG_C / 4) + c4;

    const float scx = (float)rw * (1.0f / (float)POOLSZ);
#pragma unroll
    for (int px = 0; px < POOLSZ; ++px) {
        const float srcx = ((float)px + 0.5f) * scx - 0.5f;
        const float fx   = floorf(srcx);
        const float tx   = srcx - fx;
        const int   ix   = (int)fx;
        const int   xo0  = (rx + min(max(ix,     0), rw - 1)) * (IMG_C / 4);
        const int   xo1  = (rx + min(max(ix + 1, 0), rw - 1)) * (IMG_C / 4);

        const v4f a = base[rb0 + xo0];
        const v4f b = base[rb0 + xo1];
        const v4f c = base[rb1 + xo0];
        const v4f d = base[rb1 + xo1];

        const v4f top = a + (b - a) * tx;
        const v4f bot = c + (d - c) * tx;
        dst[px * (IMG_C / 4)] = top + (bot - top) * ty;   // plain store
    }
}

extern "C" void kernel_launch(void* const* d_in, const int* in_sizes, int n_in,
                              void* d_out, int out_size, void* d_ws, size_t ws_size,
                              hipStream_t stream) {
    const float* img  = (const float*)d_in[0];
    const int*   rois = (const int*)d_in[1];
    float*       out  = (float*)d_out;
    const int R = in_sizes[1] / 4;                  // rois: (1, R, 4)
    const int n_rows = R * POOLSZ;                  // 1024*7 = 7168 blocks
    const int roisPerXcd = (R % NUM_XCD == 0) ? (R / NUM_XCD) : 0;

    int* order = nullptr;
    if (ws_size >= (size_t)R * sizeof(int)) {
        order = (int*)d_ws;
        roi_sort_kernel<<<1, 256, 0, stream>>>(rois, order, R);
    }
    roi_pool_row_kernel<<<n_rows, 256, 0, stream>>>(img, rois, out, roisPerXcd, order);
}